// Round 1
// baseline (328.637 us; speedup 1.0000x reference)
//
#include <hip/hip_runtime.h>
#include <hip/hip_bf16.h>
#include <math.h>

#define T 8
#define N 1024
#define D 128

constexpr float SCALE = 0.08838834764831845f; // 1/sqrt(128)

typedef __attribute__((ext_vector_type(8))) short short8;   // 8 bf16 (4 VGPRs)
typedef __attribute__((ext_vector_type(4))) float floatx4;  // MFMA acc / native float4

#define MFMA16(a, b, c) __builtin_amdgcn_mfma_f32_16x16x32_bf16((a), (b), (c), 0, 0, 0)

// ---------------- Kernel 0: X fp32 -> XB[t][n][d] bf16 ; XBT hi/lo [t][d][n] bf16 ----------------
__global__ __launch_bounds__(256) void convert_bf16(const float* __restrict__ X,
                                                    ushort* __restrict__ XB,
                                                    ushort* __restrict__ XBT_hi,
                                                    ushort* __restrict__ XBT_lo) {
    int idx = blockIdx.x * 256 + threadIdx.x;      // float4 index over [T*N, D/4]
    float4 v = ((const float4*)X)[idx];
    int row = idx >> 5;                            // t*N + n
    int d0  = (idx & 31) * 4;
    int t = row >> 10, n = row & 1023;
    float vv[4] = {v.x, v.y, v.z, v.w};
    ushort4 o;
    ushort* op = (ushort*)&o;
    #pragma unroll
    for (int k = 0; k < 4; ++k) {
        __hip_bfloat16 h = __float2bfloat16(vv[k]);
        float hf = __bfloat162float(h);
        __hip_bfloat16 l = __float2bfloat16(vv[k] - hf);
        op[k] = *(ushort*)&h;
        size_t toff = ((size_t)t * D + d0 + k) * N + n;
        XBT_hi[toff] = *(ushort*)&h;
        XBT_lo[toff] = *(ushort*)&l;
    }
    ((ushort4*)XB)[idx] = o;
}

// ---------------- Kernel 1: fused GAT row-block ----------------
// Block = 16 rows of one timestamp. 4 waves; wave w owns score cols [256w,256w+256).
// Phase 1: scores via 16x16x32 bf16 MFMA (A,B frags straight from L2-resident XB).
// Phase 2: mask + in-register row softmax (shuffle over m-group, LDS cross-wave).
// Phase 3: P -> LDS as compensated bf16 (hi+lo), XOR-swizzled 16B blocks.
// Phase 4: NF = P*X via 3-term compensated MFMA against XBT hi/lo.
__global__ __launch_bounds__(256) void attn_fused(const ushort* __restrict__ XB,
                                                  const ushort* __restrict__ XBT_hi,
                                                  const ushort* __restrict__ XBT_lo,
                                                  const int* __restrict__ adj,
                                                  float* __restrict__ NF) {
    const int t  = blockIdx.y;
    const int i0 = blockIdx.x * 16;
    const int tid  = threadIdx.x;
    const int wid  = tid >> 6;
    const int lane = tid & 63;
    const int m    = lane & 15;
    const int quad = lane >> 4;
    const int jbase = wid * 256;

    __shared__ ushort Ph[16][1024];    // swizzled bf16 hi
    __shared__ ushort Plo[16][1024];   // swizzled bf16 lo
    float* red = (float*)&Ph[0][0];    // aliased: [0..63] rowmax, [64..127] rowsum

    const ushort* Xt = XB + (size_t)t * N * D;

    // A-fragments for this row tile (reused across all 16 col-tiles)
    short8 afrag[4];
    {
        const ushort* pa = Xt + (size_t)(i0 + m) * D + quad * 8;
        #pragma unroll
        for (int kq = 0; kq < 4; ++kq) afrag[kq] = *(const short8*)(pa + kq * 32);
    }

    floatx4 acc[16];
    #pragma unroll
    for (int c = 0; c < 16; ++c) acc[c] = (floatx4){0.f, 0.f, 0.f, 0.f};

    // ---- Phase 1: scores ----
    #pragma unroll
    for (int c = 0; c < 16; ++c) {
        const ushort* pb = Xt + (size_t)(jbase + 16 * c + m) * D + quad * 8;
        short8 b0 = *(const short8*)(pb);
        short8 b1 = *(const short8*)(pb + 32);
        short8 b2 = *(const short8*)(pb + 64);
        short8 b3 = *(const short8*)(pb + 96);
        acc[c] = MFMA16(afrag[0], b0, acc[c]);
        acc[c] = MFMA16(afrag[1], b1, acc[c]);
        acc[c] = MFMA16(afrag[2], b2, acc[c]);
        acc[c] = MFMA16(afrag[3], b3, acc[c]);
    }

    // ---- Phase 2: mask + scale, then row softmax ----
    #pragma unroll
    for (int q = 0; q < 4; ++q) {
        const int i = i0 + quad * 4 + q;
        const int* arow = adj + (size_t)i * N + jbase + m;
        #pragma unroll
        for (int c = 0; c < 16; ++c) {
            int a = arow[16 * c];
            acc[c][q] = (a != 0) ? acc[c][q] * SCALE : -1e12f;
        }
    }

    float mx[4], inv[4];
    #pragma unroll
    for (int q = 0; q < 4; ++q) {
        float v_ = acc[0][q];
        #pragma unroll
        for (int c = 1; c < 16; ++c) v_ = fmaxf(v_, acc[c][q]);
        v_ = fmaxf(v_, __shfl_xor(v_, 1));
        v_ = fmaxf(v_, __shfl_xor(v_, 2));
        v_ = fmaxf(v_, __shfl_xor(v_, 4));
        v_ = fmaxf(v_, __shfl_xor(v_, 8));
        mx[q] = v_;
    }
    if (m == 0) {
        #pragma unroll
        for (int q = 0; q < 4; ++q) red[wid * 16 + quad * 4 + q] = mx[q];
    }
    __syncthreads();
    #pragma unroll
    for (int q = 0; q < 4; ++q) {
        int r = quad * 4 + q;
        mx[q] = fmaxf(fmaxf(red[r], red[16 + r]), fmaxf(red[32 + r], red[48 + r]));
    }

    float sm[4];
    #pragma unroll
    for (int q = 0; q < 4; ++q) {
        float s_ = 0.f;
        #pragma unroll
        for (int c = 0; c < 16; ++c) {
            float p = __expf(acc[c][q] - mx[q]);
            acc[c][q] = p;
            s_ += p;
        }
        s_ += __shfl_xor(s_, 1);
        s_ += __shfl_xor(s_, 2);
        s_ += __shfl_xor(s_, 4);
        s_ += __shfl_xor(s_, 8);
        sm[q] = s_;
    }
    if (m == 0) {
        #pragma unroll
        for (int q = 0; q < 4; ++q) red[64 + wid * 16 + quad * 4 + q] = sm[q];
    }
    __syncthreads();
    #pragma unroll
    for (int q = 0; q < 4; ++q) {
        int r = quad * 4 + q;
        inv[q] = 1.f / (red[64 + r] + red[80 + r] + red[96 + r] + red[112 + r]);
    }
    __syncthreads();   // all red reads done before Ph overwrites the region

    // ---- Phase 3: P -> LDS (compensated bf16, XOR-swizzled 16B blocks) ----
    #pragma unroll
    for (int q = 0; q < 4; ++q) {
        const int row = quad * 4 + q;
        #pragma unroll
        for (int c = 0; c < 16; ++c) {
            const int col = jbase + 16 * c + m;
            const int sc = ((((col >> 3) ^ (row & 7)) << 3) | (col & 7));
            float p = acc[c][q] * inv[q];
            __hip_bfloat16 h = __float2bfloat16(p);
            float hf = __bfloat162float(h);
            __hip_bfloat16 l = __float2bfloat16(p - hf);
            Ph[row][sc]  = *(ushort*)&h;
            Plo[row][sc] = *(ushort*)&l;
        }
    }
    __syncthreads();

    // ---- Phase 4: NF = P * X  (3-term compensated bf16 MFMA) ----
    floatx4 accN[2];
    accN[0] = (floatx4){0.f, 0.f, 0.f, 0.f};
    accN[1] = (floatx4){0.f, 0.f, 0.f, 0.f};
    const int f0 = wid * 32;
    #pragma unroll 4
    for (int kq = 0; kq < 32; ++kq) {
        const int blk = (((kq * 4 + quad) ^ (m & 7)) << 3);
        short8 ah = *(const short8*)&Ph[m][blk];
        short8 al = *(const short8*)&Plo[m][blk];
        #pragma unroll
        for (int nt = 0; nt < 2; ++nt) {
            size_t off = ((size_t)t * D + f0 + nt * 16 + m) * N + kq * 32 + quad * 8;
            short8 bh = *(const short8*)(XBT_hi + off);
            short8 bl = *(const short8*)(XBT_lo + off);
            accN[nt] = MFMA16(ah, bh, accN[nt]);
            accN[nt] = MFMA16(ah, bl, accN[nt]);
            accN[nt] = MFMA16(al, bh, accN[nt]);
        }
    }

    float* NFt = NF + (size_t)t * N * D;
    #pragma unroll
    for (int nt = 0; nt < 2; ++nt)
        #pragma unroll
        for (int q = 0; q < 4; ++q)
            NFt[(size_t)(i0 + quad * 4 + q) * D + f0 + nt * 16 + m] = accN[nt][q];
}

// ---------------- Kernel 2a: temporal gram -> sigmoid weights ----------------
// Block = one node j, 1 wave. Stage NF[:,j,:] (4 KB), lane l computes the
// (a=l&7, b=l>>3) dot in the SAME accumulation order as the old fused kernel
// (bit-identical numerics), writes W2[(b*N+j)*8 + a] = sigmoid(scale*dot).
__global__ __launch_bounds__(64) void temporal_weights(const float* __restrict__ NF,
                                                       float* __restrict__ W2) {
    const int j = blockIdx.x;
    const int lane = threadIdx.x;

    __shared__ float F[T][D + 4];               // +4 pad: distinct banks across a

    #pragma unroll
    for (int r = 0; r < 4; ++r) {
        int idx = lane + 64 * r;                // 256 float4 slots
        int a = idx >> 5, c4 = (idx & 31) * 4;
        *(float4*)(&F[a][c4]) = *(const float4*)(NF + ((size_t)a * N + j) * D + c4);
    }
    __syncthreads();

    const int a = lane & 7;
    const int b = lane >> 3;
    float s = 0.f;
    #pragma unroll
    for (int d4 = 0; d4 < 32; ++d4) {
        float4 fa = *(const float4*)(&F[a][d4 * 4]);
        float4 fb = *(const float4*)(&F[b][d4 * 4]);
        s += fa.x * fb.x + fa.y * fb.y + fa.z * fb.z + fa.w * fb.w;
    }
    float w = 1.f / (1.f + __expf(-s * SCALE));
    W2[((size_t)b * N + j) * 8 + a] = w;        // row-major by output row r=b*N+j
}

// ---------------- Kernel 2b: pure broadcast writer ----------------
// Block = one output row (b*N + j). No LDS, no barriers, no divergence:
// two uniform float4 loads (scalarizable) + 8 nontemporal float4 stores/thread.
// Structurally identical to the 6.4 TB/s fill kernel.
__global__ __launch_bounds__(256) void expand_rows(const float* __restrict__ W2,
                                                   float* __restrict__ out) {
    const int row = blockIdx.x;                 // 0..8191 = b*N + j
    const int tid = threadIdx.x;

    const float4 w0 = *(const float4*)(W2 + (size_t)row * 8);
    const float4 w1 = *(const float4*)(W2 + (size_t)row * 8 + 4);
    const float w[8] = {w0.x, w0.y, w0.z, w0.w, w1.x, w1.y, w1.z, w1.w};

    floatx4* orow = (floatx4*)(out + (size_t)row * (T * N));
    #pragma unroll
    for (int a = 0; a < T; ++a) {
        float wv = w[a];
        floatx4 v = {wv, wv, wv, wv};
        __builtin_nontemporal_store(v, orow + a * 256 + tid);
    }
}

extern "C" void kernel_launch(void* const* d_in, const int* in_sizes, int n_in,
                              void* d_out, int out_size, void* d_ws, size_t ws_size,
                              hipStream_t stream) {
    const float* X   = (const float*)d_in[0];   // [T,N,D] fp32
    const int*   adj = (const int*)d_in[1];     // [N,N] int32
    float* out = (float*)d_out;                 // [T*N, T*N] fp32

    float*  NF     = (float*)d_ws;                        // T*N*D fp32 (4 MB)
    ushort* XB     = (ushort*)(NF + (size_t)T * N * D);   // T*N*D bf16 (2 MB)
    ushort* XBT_hi = XB + (size_t)T * N * D;              // T*D*N bf16 (2 MB)
    ushort* XBT_lo = XBT_hi + (size_t)T * N * D;          // T*D*N bf16 (2 MB)
    float*  W2     = (float*)(XBT_lo + (size_t)T * N * D); // [T*N][8] fp32 (256 KB)

    convert_bf16<<<dim3(T * N * D / 4 / 256), 256, 0, stream>>>(X, XB, XBT_hi, XBT_lo);
    attn_fused<<<dim3(N / 16, T), 256, 0, stream>>>(XB, XBT_hi, XBT_lo, adj, NF);
    temporal_weights<<<dim3(N), 64, 0, stream>>>(NF, W2);
    expand_rows<<<dim3(T * N), 256, 0, stream>>>(W2, out);
}

// Round 2
// 320.075 us; speedup vs baseline: 1.0267x; 1.0267x over previous
//
#include <hip/hip_runtime.h>
#include <hip/hip_bf16.h>
#include <math.h>

#define T 8
#define N 1024
#define D 128

constexpr float SCALE = 0.08838834764831845f; // 1/sqrt(128)

typedef __attribute__((ext_vector_type(8))) short short8;   // 8 bf16 (4 VGPRs)
typedef __attribute__((ext_vector_type(4))) float floatx4;  // MFMA acc / native float4

#define MFMA16(a, b, c) __builtin_amdgcn_mfma_f32_16x16x32_bf16((a), (b), (c), 0, 0, 0)

// ---------------- Kernel 0: X fp32 -> XB[t][n][d] bf16 ; XBT hi/lo [t][d][n] bf16 ----------------
// v2: LDS-transposed so XBT stores are coalesced uint writes (was: per-thread 2B
// stores at 2KB stride = ~8 cachelines/thread of write-side transaction amplification).
// Block = (t, 64-node chunk). Stage: Hi/Lo[128 d][64 n] ushort, row stride 66
// (4B-aligned rows; stage-writes ~4-way bank conflict on a tiny phase, readback clean).
__global__ __launch_bounds__(256) void convert_bf16(const float* __restrict__ X,
                                                    ushort* __restrict__ XB,
                                                    ushort* __restrict__ XBT_hi,
                                                    ushort* __restrict__ XBT_lo) {
    const int t  = blockIdx.y;
    const int n0 = blockIdx.x * 64;
    const int tid = threadIdx.x;

    __shared__ ushort Hi[128][66];
    __shared__ ushort Lo[128][66];

    #pragma unroll
    for (int r = 0; r < 8; ++r) {
        int idx = r * 256 + tid;            // 0..2047 float4 slots of this tile
        int nl  = idx >> 5;                 // 0..63  local node
        int c4  = idx & 31;                 // float4 column
        float4 v = *(const float4*)(X + ((size_t)t * N + n0 + nl) * D + c4 * 4);
        float vv[4] = {v.x, v.y, v.z, v.w};
        ushort4 o; ushort* op = (ushort*)&o;
        #pragma unroll
        for (int k = 0; k < 4; ++k) {
            __hip_bfloat16 h = __float2bfloat16(vv[k]);
            float hf = __bfloat162float(h);
            __hip_bfloat16 l = __float2bfloat16(vv[k] - hf);
            op[k] = *(ushort*)&h;
            Hi[c4 * 4 + k][nl] = *(ushort*)&h;
            Lo[c4 * 4 + k][nl] = *(ushort*)&l;
        }
        *(ushort4*)(XB + ((size_t)t * N + n0 + nl) * D + c4 * 4) = o;
    }
    __syncthreads();

    // Coalesced writeout: per d-row, 64 ushorts = 32 uints. Half-wave covers one row.
    const int u  = tid & 31;                // uint column (2 nodes)
    const int dr = tid >> 5;                // 0..7
    #pragma unroll
    for (int p = 0; p < 16; ++p) {
        int d = p * 8 + dr;
        uint hv = *(const uint*)&Hi[d][2 * u];   // byte off = 132d + 4u, 4B-aligned
        uint lv = *(const uint*)&Lo[d][2 * u];
        size_t off = ((size_t)t * D + d) * N + n0 + 2 * u;
        *(uint*)(XBT_hi + off) = hv;
        *(uint*)(XBT_lo + off) = lv;
    }
}

// ---------------- Kernel 1: fused GAT row-block (UNCHANGED for clean attribution) ----------------
// Block = 16 rows of one timestamp. 4 waves; wave w owns score cols [256w,256w+256).
// Phase 1: scores via 16x16x32 bf16 MFMA (A,B frags straight from L2-resident XB).
// Phase 2: mask + in-register row softmax (shuffle over m-group, LDS cross-wave).
// Phase 3: P -> LDS as compensated bf16 (hi+lo), XOR-swizzled 16B blocks.
// Phase 4: NF = P*X via 3-term compensated MFMA against XBT hi/lo.
__global__ __launch_bounds__(256) void attn_fused(const ushort* __restrict__ XB,
                                                  const ushort* __restrict__ XBT_hi,
                                                  const ushort* __restrict__ XBT_lo,
                                                  const int* __restrict__ adj,
                                                  float* __restrict__ NF) {
    const int t  = blockIdx.y;
    const int i0 = blockIdx.x * 16;
    const int tid  = threadIdx.x;
    const int wid  = tid >> 6;
    const int lane = tid & 63;
    const int m    = lane & 15;
    const int quad = lane >> 4;
    const int jbase = wid * 256;

    __shared__ ushort Ph[16][1024];    // swizzled bf16 hi
    __shared__ ushort Plo[16][1024];   // swizzled bf16 lo
    float* red = (float*)&Ph[0][0];    // aliased: [0..63] rowmax, [64..127] rowsum

    const ushort* Xt = XB + (size_t)t * N * D;

    // A-fragments for this row tile (reused across all 16 col-tiles)
    short8 afrag[4];
    {
        const ushort* pa = Xt + (size_t)(i0 + m) * D + quad * 8;
        #pragma unroll
        for (int kq = 0; kq < 4; ++kq) afrag[kq] = *(const short8*)(pa + kq * 32);
    }

    floatx4 acc[16];
    #pragma unroll
    for (int c = 0; c < 16; ++c) acc[c] = (floatx4){0.f, 0.f, 0.f, 0.f};

    // ---- Phase 1: scores ----
    #pragma unroll
    for (int c = 0; c < 16; ++c) {
        const ushort* pb = Xt + (size_t)(jbase + 16 * c + m) * D + quad * 8;
        short8 b0 = *(const short8*)(pb);
        short8 b1 = *(const short8*)(pb + 32);
        short8 b2 = *(const short8*)(pb + 64);
        short8 b3 = *(const short8*)(pb + 96);
        acc[c] = MFMA16(afrag[0], b0, acc[c]);
        acc[c] = MFMA16(afrag[1], b1, acc[c]);
        acc[c] = MFMA16(afrag[2], b2, acc[c]);
        acc[c] = MFMA16(afrag[3], b3, acc[c]);
    }

    // ---- Phase 2: mask + scale, then row softmax ----
    #pragma unroll
    for (int q = 0; q < 4; ++q) {
        const int i = i0 + quad * 4 + q;
        const int* arow = adj + (size_t)i * N + jbase + m;
        #pragma unroll
        for (int c = 0; c < 16; ++c) {
            int a = arow[16 * c];
            acc[c][q] = (a != 0) ? acc[c][q] * SCALE : -1e12f;
        }
    }

    float mx[4], inv[4];
    #pragma unroll
    for (int q = 0; q < 4; ++q) {
        float v_ = acc[0][q];
        #pragma unroll
        for (int c = 1; c < 16; ++c) v_ = fmaxf(v_, acc[c][q]);
        v_ = fmaxf(v_, __shfl_xor(v_, 1));
        v_ = fmaxf(v_, __shfl_xor(v_, 2));
        v_ = fmaxf(v_, __shfl_xor(v_, 4));
        v_ = fmaxf(v_, __shfl_xor(v_, 8));
        mx[q] = v_;
    }
    if (m == 0) {
        #pragma unroll
        for (int q = 0; q < 4; ++q) red[wid * 16 + quad * 4 + q] = mx[q];
    }
    __syncthreads();
    #pragma unroll
    for (int q = 0; q < 4; ++q) {
        int r = quad * 4 + q;
        mx[q] = fmaxf(fmaxf(red[r], red[16 + r]), fmaxf(red[32 + r], red[48 + r]));
    }

    float sm[4];
    #pragma unroll
    for (int q = 0; q < 4; ++q) {
        float s_ = 0.f;
        #pragma unroll
        for (int c = 0; c < 16; ++c) {
            float p = __expf(acc[c][q] - mx[q]);
            acc[c][q] = p;
            s_ += p;
        }
        s_ += __shfl_xor(s_, 1);
        s_ += __shfl_xor(s_, 2);
        s_ += __shfl_xor(s_, 4);
        s_ += __shfl_xor(s_, 8);
        sm[q] = s_;
    }
    if (m == 0) {
        #pragma unroll
        for (int q = 0; q < 4; ++q) red[64 + wid * 16 + quad * 4 + q] = sm[q];
    }
    __syncthreads();
    #pragma unroll
    for (int q = 0; q < 4; ++q) {
        int r = quad * 4 + q;
        inv[q] = 1.f / (red[64 + r] + red[80 + r] + red[96 + r] + red[112 + r]);
    }
    __syncthreads();   // all red reads done before Ph overwrites the region

    // ---- Phase 3: P -> LDS (compensated bf16, XOR-swizzled 16B blocks) ----
    #pragma unroll
    for (int q = 0; q < 4; ++q) {
        const int row = quad * 4 + q;
        #pragma unroll
        for (int c = 0; c < 16; ++c) {
            const int col = jbase + 16 * c + m;
            const int sc = ((((col >> 3) ^ (row & 7)) << 3) | (col & 7));
            float p = acc[c][q] * inv[q];
            __hip_bfloat16 h = __float2bfloat16(p);
            float hf = __bfloat162float(h);
            __hip_bfloat16 l = __float2bfloat16(p - hf);
            Ph[row][sc]  = *(ushort*)&h;
            Plo[row][sc] = *(ushort*)&l;
        }
    }
    __syncthreads();

    // ---- Phase 4: NF = P * X  (3-term compensated bf16 MFMA) ----
    floatx4 accN[2];
    accN[0] = (floatx4){0.f, 0.f, 0.f, 0.f};
    accN[1] = (floatx4){0.f, 0.f, 0.f, 0.f};
    const int f0 = wid * 32;
    #pragma unroll 4
    for (int kq = 0; kq < 32; ++kq) {
        const int blk = (((kq * 4 + quad) ^ (m & 7)) << 3);
        short8 ah = *(const short8*)&Ph[m][blk];
        short8 al = *(const short8*)&Plo[m][blk];
        #pragma unroll
        for (int nt = 0; nt < 2; ++nt) {
            size_t off = ((size_t)t * D + f0 + nt * 16 + m) * N + kq * 32 + quad * 8;
            short8 bh = *(const short8*)(XBT_hi + off);
            short8 bl = *(const short8*)(XBT_lo + off);
            accN[nt] = MFMA16(ah, bh, accN[nt]);
            accN[nt] = MFMA16(ah, bl, accN[nt]);
            accN[nt] = MFMA16(al, bh, accN[nt]);
        }
    }

    float* NFt = NF + (size_t)t * N * D;
    #pragma unroll
    for (int nt = 0; nt < 2; ++nt)
        #pragma unroll
        for (int q = 0; q < 4; ++q)
            NFt[(size_t)(i0 + quad * 4 + q) * D + f0 + nt * 16 + m] = accN[nt][q];
}

// ---------------- Kernel 2: fused temporal-gram + sigmoid + broadcast-expand ----------------
// Re-fused (round-0 form): per-block serial dot phase is hidden by inter-block TLP
// (proved by round-1 A/B: split version identical perf, one extra launch).
__global__ __launch_bounds__(256) void expand_fused(const float* __restrict__ NF,
                                                    float* __restrict__ out) {
    const int row = blockIdx.x;                 // 0..8191 = b*N + j
    const int b = row >> 10, j = row & 1023;
    const int tid = threadIdx.x;

    __shared__ float F[T][D + 4];               // +4 pad: lanes a=0..7 hit distinct banks
    __shared__ float w[T];

    {   // stage NF[a][j][:] — 256 threads x float4 = 4 KB
        int a = tid >> 5, c4 = (tid & 31) * 4;
        *(float4*)(&F[a][c4]) = *(const float4*)(NF + ((size_t)a * N + j) * D + c4);
    }
    __syncthreads();

    if (tid < T) {                              // 8 lanes: dot(F[tid], F[b])
        float s = 0.f;
        #pragma unroll
        for (int d4 = 0; d4 < 32; ++d4) {
            float4 fa = *(const float4*)(&F[tid][d4 * 4]);
            float4 fb = *(const float4*)(&F[b][d4 * 4]);
            s += fa.x * fb.x + fa.y * fb.y + fa.z * fb.z + fa.w * fb.w;
        }
        w[tid] = 1.f / (1.f + __expf(-s * SCALE));
    }
    __syncthreads();

    floatx4* orow = (floatx4*)(out + (size_t)row * (T * N));
    #pragma unroll
    for (int a = 0; a < T; ++a) {
        float wv = w[a];
        floatx4 v = {wv, wv, wv, wv};
        __builtin_nontemporal_store(v, orow + a * 256 + tid);
    }
}

extern "C" void kernel_launch(void* const* d_in, const int* in_sizes, int n_in,
                              void* d_out, int out_size, void* d_ws, size_t ws_size,
                              hipStream_t stream) {
    const float* X   = (const float*)d_in[0];   // [T,N,D] fp32
    const int*   adj = (const int*)d_in[1];     // [N,N] int32
    float* out = (float*)d_out;                 // [T*N, T*N] fp32

    float*  NF     = (float*)d_ws;                        // T*N*D fp32 (4 MB)
    ushort* XB     = (ushort*)(NF + (size_t)T * N * D);   // T*N*D bf16 (2 MB)
    ushort* XBT_hi = XB + (size_t)T * N * D;              // T*D*N bf16 (2 MB)
    ushort* XBT_lo = XBT_hi + (size_t)T * N * D;          // T*D*N bf16 (2 MB)

    convert_bf16<<<dim3(N / 64, T), 256, 0, stream>>>(X, XB, XBT_hi, XBT_lo);
    attn_fused<<<dim3(N / 16, T), 256, 0, stream>>>(XB, XBT_hi, XBT_lo, adj, NF);
    expand_fused<<<dim3(T * N), 256, 0, stream>>>(NF, out);
}